// Round 7
// baseline (480.407 us; speedup 1.0000x reference)
//
#include <hip/hip_runtime.h>

// ---------------------------------------------------------------------------
// GridNet fused forward: MLP (fp8/bf16 MFMA) + softmax + 5x5 gather + sigmoid
// B=262144, GS=(1024,2048), NS=5, layers 2-64-256-512-256-64-75
// R7: fp8 e4m3 acts+weights for L2..L5 (mfma_f32_16x16x32_fp8_fp8; same rate
//     as bf16). Halves LDS B-traffic (392 KB/block vs 1256), makes full h3
//     fit (no split-K L4, no acc co-residency), and shrinks LDS to 52.5 KB
//     -> 3 blocks/CU (was 2). L6 kept bf16 for output accuracy. L1 f32 VALU.
//     R6: 194us, MfmaUtil 37%, LDS-read pipe binding at ~53% util.
// ---------------------------------------------------------------------------

#define PI_F     3.14159265358979323846f
#define TWO_PI_F 6.28318530717958647692f

typedef __attribute__((ext_vector_type(8))) short bf16x8;   // 8 bf16 = 4 VGPRs
typedef __attribute__((ext_vector_type(4))) short bf16x4;   // 8 B packed
typedef __attribute__((ext_vector_type(4))) float f32x4;    // MFMA C/D frag
typedef __attribute__((ext_vector_type(2))) int   i32x2;

__device__ __forceinline__ short f2bf(float f) {
    unsigned u = __builtin_bit_cast(unsigned, f);
    u += 0x7fffu + ((u >> 16) & 1u);            // round-nearest-even
    return (short)(u >> 16);
}

template<bool B, class T1, class T2> struct Cond { using T = T1; };
template<class T1, class T2> struct Cond<false, T1, T2> { using T = T2; };

__device__ __forceinline__ f32x4 mf(long a, long b, f32x4 c) {
    return __builtin_amdgcn_mfma_f32_16x16x32_fp8_fp8(a, b, c, 0, 0, 0);
}
__device__ __forceinline__ f32x4 mf(bf16x8 a, bf16x8 b, f32x4 c) {
    return __builtin_amdgcn_mfma_f32_16x16x32_bf16(a, b, c, 0, 0, 0);
}

// ws layout (BYTES). fp8 weights fragment-packed for MFMA A-operand:
//   frag f = ot*KTS + kt, 512 B; byte lane*8+e <-> W[k=kt*32+(lane>>4)*8+e][n=ot*16+(lane&15)]
// F2 (w2 fp8, 64x256,  KTS=2)          @ 0       (16384)
// F3 (w3 fp8, 256x512, 2 od-halves,
//     per half KTS=8, 16 ot)           @ 16384   (131072; half stride 65536)
// F4 (w4 fp8, 512x256, KTS=16)         @ 147456  (131072)
// F5 (w5 fp8, 256x64,  KTS=8)          @ 278528  (16384)
// F6 (w6 bf16 frags, 64x80, KTS=2)     @ 294912  (10240; cols 75..79 zero)
// b6pad (80 f32)                       @ 305152  (320)
#define F2_OFF 0
#define F3_OFF 16384
#define F4_OFF 147456
#define F5_OFF 278528
#define F6_OFF 294912
#define B6_OFF 305152
#define PREP_TOTAL 300112   // 294912 fp8 bytes + 5120 bf16 shorts + 80 f32

__global__ void prep_weights(const float* __restrict__ w2, const float* __restrict__ w3,
                             const float* __restrict__ w4, const float* __restrict__ w5,
                             const float* __restrict__ w6, const float* __restrict__ b6,
                             char* __restrict__ ws) {
    int idx = blockIdx.x * blockDim.x + threadIdx.x;
    if (idx >= PREP_TOTAL) return;
    if (idx < F6_OFF) {                          // fp8 sections, one byte each
        int lane = (idx >> 3) & 63, e = idx & 7;
        int f, kt, ot, n, k; float v;
        if (idx < F3_OFF) {
            f = idx >> 9; kt = f & 1; ot = f >> 1;
            n = ot * 16 + (lane & 15); k = kt * 32 + (lane >> 4) * 8 + e;
            v = w2[k * 256 + n];
        } else if (idx < F4_OFF) {
            int rel = idx - F3_OFF; int half = rel >> 16; int r2 = rel & 65535;
            f = r2 >> 9; kt = f & 7; ot = f >> 3;
            n = half * 256 + ot * 16 + (lane & 15); k = kt * 32 + (lane >> 4) * 8 + e;
            v = w3[k * 512 + n];
        } else if (idx < F5_OFF) {
            int rel = idx - F4_OFF; f = rel >> 9; kt = f & 15; ot = f >> 4;
            n = ot * 16 + (lane & 15); k = kt * 32 + (lane >> 4) * 8 + e;
            v = w4[k * 256 + n];
        } else {
            int rel = idx - F5_OFF; f = rel >> 9; kt = f & 7; ot = f >> 3;
            n = ot * 16 + (lane & 15); k = kt * 32 + (lane >> 4) * 8 + e;
            v = w5[k * 64 + n];
        }
        ws[idx] = (char)(__builtin_amdgcn_cvt_pk_fp8_f32(v, v, 0, false) & 0xff);
    } else if (idx < F6_OFF + 5120) {            // w6 bf16 frags (shorts)
        int s = idx - F6_OFF;
        int f = s >> 9, r = s & 511, lane = r >> 3, e = r & 7;
        int kt = f & 1, ot = f >> 1;
        int n = ot * 16 + (lane & 15), k = kt * 32 + (lane >> 4) * 8 + e;
        float v = (n < 75) ? w6[k * 75 + n] : 0.0f;
        ((short*)(ws + F6_OFF))[s] = f2bf(v);
    } else {                                     // padded bias6
        int n = idx - (F6_OFF + 5120);
        ((float*)(ws + B6_OFF))[n] = (n < 75) ? b6[n] : 0.0f;
    }
}

// Role-swapped layer: D[od][pt] = sum_k W^T[od][k] * act[k][pt] (+bias[od])
// Fragment-packed A (global) and B (LDS), frag = 512 B (fp8) / 1024 B (bf16).
// 8 waves split OG od-groups x PTG pt-groups. OM: 0=fp8-FP out, 1=bf16-FP out,
// 2=f32 plain (stride 80). otb0 = global od-tile offset (L3 half 1).
template<bool FP8, int K, int MT, int NT, int PTG, int OG, int KTS, int OUTKI,
         bool RELU, int OM>
__device__ __forceinline__ void layer(const char* __restrict__ act, char* __restrict__ outP,
                                      const char* __restrict__ pack,
                                      const float* __restrict__ bias,
                                      const int otb0, const int wave, const int lane) {
    constexpr int KT = K / 32;
    constexpr int FB = FP8 ? 512 : 1024;     // frag bytes
    constexpr int LB = FB / 64;              // bytes per lane per frag
    using frag_t = typename Cond<FP8, long, bf16x8>::T;
    const int og = wave / PTG;
    if (og >= OG) return;
    const int pg  = wave % PTG;
    const int ptb = pg * (NT * 16);
    const int tj0 = ptb >> 4;
    const int otb = og * MT;
    const int lr = lane & 15, lq = lane >> 4;

    f32x4 acc[MT][NT];
    #pragma unroll
    for (int i = 0; i < MT; ++i) {
        f32x4 bv = *(const f32x4*)(bias + (otb0 + otb + i) * 16 + lq * 4);
        #pragma unroll
        for (int j = 0; j < NT; ++j) acc[i][j] = bv;
    }

    const char* ap = pack + (otb * KTS) * FB + lane * LB;
    const char* bp = act + (tj0 * KT) * FB + lane * LB;

    frag_t a[MT], b[NT];
    #pragma unroll
    for (int i = 0; i < MT; ++i) a[i] = *(const frag_t*)(ap + (i * KTS) * FB);
    #pragma unroll
    for (int j = 0; j < NT; ++j) b[j] = *(const frag_t*)(bp + (j * KT) * FB);

    #pragma unroll
    for (int kt = 0; kt < KT - 1; ++kt) {
        frag_t a2[MT], b2[NT];
        #pragma unroll
        for (int i = 0; i < MT; ++i) a2[i] = *(const frag_t*)(ap + (i * KTS + kt + 1) * FB);
        #pragma unroll
        for (int j = 0; j < NT; ++j) b2[j] = *(const frag_t*)(bp + (j * KT + kt + 1) * FB);
        #pragma unroll
        for (int i = 0; i < MT; ++i) {
            #pragma unroll
            for (int j = 0; j < NT; ++j) acc[i][j] = mf(a[i], b[j], acc[i][j]);
        }
        #pragma unroll
        for (int i = 0; i < MT; ++i) a[i] = a2[i];
        #pragma unroll
        for (int j = 0; j < NT; ++j) b[j] = b2[j];
    }
    #pragma unroll
    for (int i = 0; i < MT; ++i) {
        #pragma unroll
        for (int j = 0; j < NT; ++j) acc[i][j] = mf(a[i], b[j], acc[i][j]);
    }

    #pragma unroll
    for (int i = 0; i < MT; ++i) {
        const int o0  = (otb0 + otb + i) * 16 + lq * 4;   // global out dim (4 consec)
        const int c   = o0 >> 5;                          // out k-tile
        const int kk3 = (o0 >> 3) & 3;
        const int e0  = o0 & 7;                           // 0 or 4
        #pragma unroll
        for (int j = 0; j < NT; ++j) {
            f32x4 v = acc[i][j];
            if (RELU) {
                v[0] = fmaxf(v[0], 0.0f); v[1] = fmaxf(v[1], 0.0f);
                v[2] = fmaxf(v[2], 0.0f); v[3] = fmaxf(v[3], 0.0f);
            }
            if (OM == 2) {
                const int row = ptb + j * 16 + lr;
                *(f32x4*)((float*)outP + row * 80 + o0) = v;
            } else if (OM == 0) {
                int pk = __builtin_amdgcn_cvt_pk_fp8_f32(v[0], v[1], 0, false);
                pk = __builtin_amdgcn_cvt_pk_fp8_f32(v[2], v[3], pk, true);
                *(int*)(outP + ((tj0 + j) * OUTKI + c) * 512 + (kk3 * 16 + lr) * 8 + e0) = pk;
            } else {
                bf16x4 pk = (bf16x4){ f2bf(v[0]), f2bf(v[1]), f2bf(v[2]), f2bf(v[3]) };
                *(bf16x4*)((short*)outP + ((tj0 + j) * OUTKI + c) * 512 + (kk3 * 16 + lr) * 8 + e0) = pk;
            }
        }
    }
}

__global__ __launch_bounds__(512, 6) void gridnet_fused(
    const float* __restrict__ pos, const float* __restrict__ grid_pos,
    const float* __restrict__ w1, const float* __restrict__ b1,
    const float* __restrict__ b2, const float* __restrict__ b3,
    const float* __restrict__ b4, const float* __restrict__ b5,
    const char* __restrict__ ws, float* __restrict__ out) {

    // H: h1 fp8 @0 (4KB), h2 fp8 @4096 (16KB); h4 fp8 reuses @0 (16KB).
    // G: h3 fp8 (32KB); then h5 bf16 @0 (8KB) and logits f32 @8192 (20KB).
    // Total 20480 + 32768 + 512 = 53760 B <= 54613 -> 3 blocks/CU.
    __shared__ __align__(16) char H[20480];
    __shared__ __align__(16) char G[32768];
    __shared__ float posS[128];

    const int tid  = threadIdx.x;
    const int wave = tid >> 6;
    const int lane = tid & 63;
    const int m0   = blockIdx.x * 64;

    if (tid < 128) posS[tid] = pos[m0 * 2 + tid];
    __syncthreads();

    // ---- layer 1 (2 -> 64) f32 VALU -> h1 fp8, fragment-packed (KI=2) ----
    {
        const int m = tid >> 3, g = tid & 7, n0 = g * 8;
        f32x4 wa0 = *(const f32x4*)(w1 + n0);
        f32x4 wa1 = *(const f32x4*)(w1 + n0 + 4);
        f32x4 wb0 = *(const f32x4*)(w1 + 64 + n0);
        f32x4 wb1 = *(const f32x4*)(w1 + 64 + n0 + 4);
        f32x4 bb0 = *(const f32x4*)(b1 + n0);
        f32x4 bb1 = *(const f32x4*)(b1 + n0 + 4);
        const float p0 = posS[m * 2 + 0], p1 = posS[m * 2 + 1];
        float r[8];
        #pragma unroll
        for (int i = 0; i < 4; ++i)
            r[i]     = fmaxf(fmaf(p0, wa0[i], fmaf(p1, wb0[i], bb0[i])), 0.0f);
        #pragma unroll
        for (int i = 0; i < 4; ++i)
            r[4 + i] = fmaxf(fmaf(p0, wa1[i], fmaf(p1, wb1[i], bb1[i])), 0.0f);
        int i0 = __builtin_amdgcn_cvt_pk_fp8_f32(r[0], r[1], 0, false);
        i0     = __builtin_amdgcn_cvt_pk_fp8_f32(r[2], r[3], i0, true);
        int i1 = __builtin_amdgcn_cvt_pk_fp8_f32(r[4], r[5], 0, false);
        i1     = __builtin_amdgcn_cvt_pk_fp8_f32(r[6], r[7], i1, true);
        const int t = m >> 4, c = n0 >> 5, kk = n0 & 31;
        *(i32x2*)(H + (t * 2 + c) * 512 + ((kk >> 3) * 16 + (m & 15)) * 8) = (i32x2){i0, i1};
    }
    __syncthreads();

    // L2: 64 -> 256 (fp8)
    layer<true,  64, 2, 4, 1, 8,  2,  8, true,  0>(H, H + 4096, ws + F2_OFF, b2, 0, wave, lane);
    __syncthreads();
    // L3: 256 -> 512 (fp8), two od-halves, full h3 -> G (no split-K L4 needed)
    layer<true, 256, 4, 2, 2, 4,  8, 16, true,  0>(H + 4096, G, ws + F3_OFF,         b3,  0, wave, lane);
    layer<true, 256, 4, 2, 2, 4,  8, 16, true,  0>(H + 4096, G, ws + F3_OFF + 65536, b3, 16, wave, lane);
    __syncthreads();
    // L4: 512 -> 256 (fp8), full K in one pass
    layer<true, 512, 4, 2, 2, 4, 16,  8, true,  0>(G, H, ws + F4_OFF, b4, 0, wave, lane);
    __syncthreads();
    // L5: 256 -> 64 (fp8 in, bf16-FP out)
    layer<true, 256, 1, 2, 2, 4,  8,  2, true,  1>(H, G, ws + F5_OFF, b5, 0, wave, lane);
    __syncthreads();
    // L6: 64 -> 80 logits (bf16 in, f32 plain out @ G+8192)
    layer<false, 64, 1, 4, 1, 5,  2,  0, false, 2>(G, G + 8192, ws + F6_OFF,
                                                   (const float*)(ws + B6_OFF), 0, wave, lane);
    __syncthreads();

    // ---- epilogue: softmax(75) + 5x5x3 gather + sigmoid, 8 lanes per point ----
    const float* logitsS = (const float*)(G + 8192);
    const int p = tid >> 3;              // point within tile
    const int s = tid & 7;               // sub-lane
    const float p0 = posS[p * 2 + 0], p1 = posS[p * 2 + 1];
    const int tx0 = (int)(p0 / PI_F * 1023.0f);                 // == int(gx), ix = tx0 + dy
    const int ty0 = (int)((p1 + PI_F) / TWO_PI_F * 2047.0f);    // == int(gy), iy = ty0 + dx

    const float* lrow = logitsS + p * 80;
    float lv[10];
    float mx = -1e30f;
    #pragma unroll
    for (int i = 0; i < 10; ++i) {
        int f = s + i * 8;
        float v = (f < 75) ? lrow[f] : -1e30f;
        lv[i] = v;
        mx = fmaxf(mx, v);
    }
    mx = fmaxf(mx, __shfl_xor(mx, 1, 8));
    mx = fmaxf(mx, __shfl_xor(mx, 2, 8));
    mx = fmaxf(mx, __shfl_xor(mx, 4, 8));

    float den = 0.0f, x0 = 0.0f, x1 = 0.0f, x2 = 0.0f;
    #pragma unroll
    for (int i = 0; i < 10; ++i) {
        int f = s + i * 8;
        if (f < 75) {
            float e = __expf(lv[i] - mx);
            den += e;
            int c = f / 25, rr = f % 25, dy = rr / 5, dx = rr % 5;
            float g = grid_pos[((tx0 + dy) * 2052 + (ty0 + dx)) * 3 + c];
            if      (c == 0) x0 += e * g;
            else if (c == 1) x1 += e * g;
            else             x2 += e * g;
        }
    }
    #pragma unroll
    for (int mask = 1; mask < 8; mask <<= 1) {
        den += __shfl_xor(den, mask, 8);
        x0  += __shfl_xor(x0,  mask, 8);
        x1  += __shfl_xor(x1,  mask, 8);
        x2  += __shfl_xor(x2,  mask, 8);
    }
    if (s < 3) {
        float xv = (s == 0) ? x0 : (s == 1 ? x1 : x2);
        xv /= den;
        float sig = 1.0f / (1.0f + __expf(-xv));
        out[(m0 + p) * 3 + s] = (sig > 0.1f) ? sig * 255.0f : 0.0f;
    }
}

extern "C" void kernel_launch(void* const* d_in, const int* in_sizes, int n_in,
                              void* d_out, int out_size, void* d_ws, size_t ws_size,
                              hipStream_t stream) {
    const float* pos      = (const float*)d_in[0];
    const float* grid_pos = (const float*)d_in[1];
    const float* w1 = (const float*)d_in[2];
    const float* b1 = (const float*)d_in[3];
    const float* w2 = (const float*)d_in[4];
    const float* b2 = (const float*)d_in[5];
    const float* w3 = (const float*)d_in[6];
    const float* b3 = (const float*)d_in[7];
    const float* w4 = (const float*)d_in[8];
    const float* b4 = (const float*)d_in[9];
    const float* w5 = (const float*)d_in[10];
    const float* b5 = (const float*)d_in[11];
    const float* w6 = (const float*)d_in[12];
    const float* b6 = (const float*)d_in[13];
    char* ws = (char*)d_ws;
    float* out = (float*)d_out;

    prep_weights<<<(PREP_TOTAL + 255) / 256, 256, 0, stream>>>(w2, w3, w4, w5, w6, b6, ws);
    gridnet_fused<<<262144 / 64, 512, 0, stream>>>(pos, grid_pos, w1, b1, b2, b3, b4, b5, ws, out);
}

// Round 8
// 279.622 us; speedup vs baseline: 1.7181x; 1.7181x over previous
//
#include <hip/hip_runtime.h>

// ---------------------------------------------------------------------------
// GridNet fused forward: MLP (fp8/bf16 MFMA) + softmax + 5x5 gather + sigmoid
// B=262144, GS=(1024,2048), NS=5, layers 2-64-256-512-256-64-75
// R8: revert launch bounds (512,6)->(512,4). R7's 6-waves/EU cap = 84 regs
//     forced ~360 B/thread scratch spill (WRITE_SIZE 3->740 MB, HBM 38% peak,
//     dur 414us). fp8 structure unchanged: L2..L5 e4m3 acts+weights
//     (mfma_f32_16x16x32_fp8_fp8), full h3 (no split-K), LDS 53.8 KB.
//     2 blocks/CU (VGPR-limited) is acceptable: fp8 halved the LDS pipe load.
// ---------------------------------------------------------------------------

#define PI_F     3.14159265358979323846f
#define TWO_PI_F 6.28318530717958647692f

typedef __attribute__((ext_vector_type(8))) short bf16x8;   // 8 bf16 = 4 VGPRs
typedef __attribute__((ext_vector_type(4))) short bf16x4;   // 8 B packed
typedef __attribute__((ext_vector_type(4))) float f32x4;    // MFMA C/D frag
typedef __attribute__((ext_vector_type(2))) int   i32x2;

__device__ __forceinline__ short f2bf(float f) {
    unsigned u = __builtin_bit_cast(unsigned, f);
    u += 0x7fffu + ((u >> 16) & 1u);            // round-nearest-even
    return (short)(u >> 16);
}

template<bool B, class T1, class T2> struct Cond { using T = T1; };
template<class T1, class T2> struct Cond<false, T1, T2> { using T = T2; };

__device__ __forceinline__ f32x4 mf(long a, long b, f32x4 c) {
    return __builtin_amdgcn_mfma_f32_16x16x32_fp8_fp8(a, b, c, 0, 0, 0);
}
__device__ __forceinline__ f32x4 mf(bf16x8 a, bf16x8 b, f32x4 c) {
    return __builtin_amdgcn_mfma_f32_16x16x32_bf16(a, b, c, 0, 0, 0);
}

// ws layout (BYTES). fp8 weights fragment-packed for MFMA A-operand:
//   frag f = ot*KTS + kt, 512 B; byte lane*8+e <-> W[k=kt*32+(lane>>4)*8+e][n=ot*16+(lane&15)]
// F2 (w2 fp8, 64x256,  KTS=2)          @ 0       (16384)
// F3 (w3 fp8, 256x512, 2 od-halves,
//     per half KTS=8, 16 ot)           @ 16384   (131072; half stride 65536)
// F4 (w4 fp8, 512x256, KTS=16)         @ 147456  (131072)
// F5 (w5 fp8, 256x64,  KTS=8)          @ 278528  (16384)
// F6 (w6 bf16 frags, 64x80, KTS=2)     @ 294912  (10240; cols 75..79 zero)
// b6pad (80 f32)                       @ 305152  (320)
#define F2_OFF 0
#define F3_OFF 16384
#define F4_OFF 147456
#define F5_OFF 278528
#define F6_OFF 294912
#define B6_OFF 305152
#define PREP_TOTAL 300112   // 294912 fp8 bytes + 5120 bf16 shorts + 80 f32

__global__ void prep_weights(const float* __restrict__ w2, const float* __restrict__ w3,
                             const float* __restrict__ w4, const float* __restrict__ w5,
                             const float* __restrict__ w6, const float* __restrict__ b6,
                             char* __restrict__ ws) {
    int idx = blockIdx.x * blockDim.x + threadIdx.x;
    if (idx >= PREP_TOTAL) return;
    if (idx < F6_OFF) {                          // fp8 sections, one byte each
        int lane = (idx >> 3) & 63, e = idx & 7;
        int f, kt, ot, n, k; float v;
        if (idx < F3_OFF) {
            f = idx >> 9; kt = f & 1; ot = f >> 1;
            n = ot * 16 + (lane & 15); k = kt * 32 + (lane >> 4) * 8 + e;
            v = w2[k * 256 + n];
        } else if (idx < F4_OFF) {
            int rel = idx - F3_OFF; int half = rel >> 16; int r2 = rel & 65535;
            f = r2 >> 9; kt = f & 7; ot = f >> 3;
            n = half * 256 + ot * 16 + (lane & 15); k = kt * 32 + (lane >> 4) * 8 + e;
            v = w3[k * 512 + n];
        } else if (idx < F5_OFF) {
            int rel = idx - F4_OFF; f = rel >> 9; kt = f & 15; ot = f >> 4;
            n = ot * 16 + (lane & 15); k = kt * 32 + (lane >> 4) * 8 + e;
            v = w4[k * 256 + n];
        } else {
            int rel = idx - F5_OFF; f = rel >> 9; kt = f & 7; ot = f >> 3;
            n = ot * 16 + (lane & 15); k = kt * 32 + (lane >> 4) * 8 + e;
            v = w5[k * 64 + n];
        }
        ws[idx] = (char)(__builtin_amdgcn_cvt_pk_fp8_f32(v, v, 0, false) & 0xff);
    } else if (idx < F6_OFF + 5120) {            // w6 bf16 frags (shorts)
        int s = idx - F6_OFF;
        int f = s >> 9, r = s & 511, lane = r >> 3, e = r & 7;
        int kt = f & 1, ot = f >> 1;
        int n = ot * 16 + (lane & 15), k = kt * 32 + (lane >> 4) * 8 + e;
        float v = (n < 75) ? w6[k * 75 + n] : 0.0f;
        ((short*)(ws + F6_OFF))[s] = f2bf(v);
    } else {                                     // padded bias6
        int n = idx - (F6_OFF + 5120);
        ((float*)(ws + B6_OFF))[n] = (n < 75) ? b6[n] : 0.0f;
    }
}

// Role-swapped layer: D[od][pt] = sum_k W^T[od][k] * act[k][pt] (+bias[od])
// Fragment-packed A (global) and B (LDS), frag = 512 B (fp8) / 1024 B (bf16).
// 8 waves split OG od-groups x PTG pt-groups. OM: 0=fp8-FP out, 1=bf16-FP out,
// 2=f32 plain (stride 80). otb0 = global od-tile offset (L3 half 1).
template<bool FP8, int K, int MT, int NT, int PTG, int OG, int KTS, int OUTKI,
         bool RELU, int OM>
__device__ __forceinline__ void layer(const char* __restrict__ act, char* __restrict__ outP,
                                      const char* __restrict__ pack,
                                      const float* __restrict__ bias,
                                      const int otb0, const int wave, const int lane) {
    constexpr int KT = K / 32;
    constexpr int FB = FP8 ? 512 : 1024;     // frag bytes
    constexpr int LB = FB / 64;              // bytes per lane per frag
    using frag_t = typename Cond<FP8, long, bf16x8>::T;
    const int og = wave / PTG;
    if (og >= OG) return;
    const int pg  = wave % PTG;
    const int ptb = pg * (NT * 16);
    const int tj0 = ptb >> 4;
    const int otb = og * MT;
    const int lr = lane & 15, lq = lane >> 4;

    f32x4 acc[MT][NT];
    #pragma unroll
    for (int i = 0; i < MT; ++i) {
        f32x4 bv = *(const f32x4*)(bias + (otb0 + otb + i) * 16 + lq * 4);
        #pragma unroll
        for (int j = 0; j < NT; ++j) acc[i][j] = bv;
    }

    const char* ap = pack + (otb * KTS) * FB + lane * LB;
    const char* bp = act + (tj0 * KT) * FB + lane * LB;

    frag_t a[MT], b[NT];
    #pragma unroll
    for (int i = 0; i < MT; ++i) a[i] = *(const frag_t*)(ap + (i * KTS) * FB);
    #pragma unroll
    for (int j = 0; j < NT; ++j) b[j] = *(const frag_t*)(bp + (j * KT) * FB);

    #pragma unroll
    for (int kt = 0; kt < KT - 1; ++kt) {
        frag_t a2[MT], b2[NT];
        #pragma unroll
        for (int i = 0; i < MT; ++i) a2[i] = *(const frag_t*)(ap + (i * KTS + kt + 1) * FB);
        #pragma unroll
        for (int j = 0; j < NT; ++j) b2[j] = *(const frag_t*)(bp + (j * KT + kt + 1) * FB);
        #pragma unroll
        for (int i = 0; i < MT; ++i) {
            #pragma unroll
            for (int j = 0; j < NT; ++j) acc[i][j] = mf(a[i], b[j], acc[i][j]);
        }
        #pragma unroll
        for (int i = 0; i < MT; ++i) a[i] = a2[i];
        #pragma unroll
        for (int j = 0; j < NT; ++j) b[j] = b2[j];
    }
    #pragma unroll
    for (int i = 0; i < MT; ++i) {
        #pragma unroll
        for (int j = 0; j < NT; ++j) acc[i][j] = mf(a[i], b[j], acc[i][j]);
    }

    #pragma unroll
    for (int i = 0; i < MT; ++i) {
        const int o0  = (otb0 + otb + i) * 16 + lq * 4;   // global out dim (4 consec)
        const int c   = o0 >> 5;                          // out k-tile
        const int kk3 = (o0 >> 3) & 3;
        const int e0  = o0 & 7;                           // 0 or 4
        #pragma unroll
        for (int j = 0; j < NT; ++j) {
            f32x4 v = acc[i][j];
            if (RELU) {
                v[0] = fmaxf(v[0], 0.0f); v[1] = fmaxf(v[1], 0.0f);
                v[2] = fmaxf(v[2], 0.0f); v[3] = fmaxf(v[3], 0.0f);
            }
            if (OM == 2) {
                const int row = ptb + j * 16 + lr;
                *(f32x4*)((float*)outP + row * 80 + o0) = v;
            } else if (OM == 0) {
                int pk = __builtin_amdgcn_cvt_pk_fp8_f32(v[0], v[1], 0, false);
                pk = __builtin_amdgcn_cvt_pk_fp8_f32(v[2], v[3], pk, true);
                *(int*)(outP + ((tj0 + j) * OUTKI + c) * 512 + (kk3 * 16 + lr) * 8 + e0) = pk;
            } else {
                bf16x4 pk = (bf16x4){ f2bf(v[0]), f2bf(v[1]), f2bf(v[2]), f2bf(v[3]) };
                *(bf16x4*)((short*)outP + ((tj0 + j) * OUTKI + c) * 512 + (kk3 * 16 + lr) * 8 + e0) = pk;
            }
        }
    }
}

__global__ __launch_bounds__(512, 4) void gridnet_fused(
    const float* __restrict__ pos, const float* __restrict__ grid_pos,
    const float* __restrict__ w1, const float* __restrict__ b1,
    const float* __restrict__ b2, const float* __restrict__ b3,
    const float* __restrict__ b4, const float* __restrict__ b5,
    const char* __restrict__ ws, float* __restrict__ out) {

    // H: h1 fp8 @0 (4KB), h2 fp8 @4096 (16KB); h4 fp8 reuses @0 (16KB).
    // G: h3 fp8 (32KB); then h5 bf16 @0 (8KB) and logits f32 @8192 (20KB).
    // Total 53760 B.
    __shared__ __align__(16) char H[20480];
    __shared__ __align__(16) char G[32768];
    __shared__ float posS[128];

    const int tid  = threadIdx.x;
    const int wave = tid >> 6;
    const int lane = tid & 63;
    const int m0   = blockIdx.x * 64;

    if (tid < 128) posS[tid] = pos[m0 * 2 + tid];
    __syncthreads();

    // ---- layer 1 (2 -> 64) f32 VALU -> h1 fp8, fragment-packed (KI=2) ----
    {
        const int m = tid >> 3, g = tid & 7, n0 = g * 8;
        f32x4 wa0 = *(const f32x4*)(w1 + n0);
        f32x4 wa1 = *(const f32x4*)(w1 + n0 + 4);
        f32x4 wb0 = *(const f32x4*)(w1 + 64 + n0);
        f32x4 wb1 = *(const f32x4*)(w1 + 64 + n0 + 4);
        f32x4 bb0 = *(const f32x4*)(b1 + n0);
        f32x4 bb1 = *(const f32x4*)(b1 + n0 + 4);
        const float p0 = posS[m * 2 + 0], p1 = posS[m * 2 + 1];
        float r[8];
        #pragma unroll
        for (int i = 0; i < 4; ++i)
            r[i]     = fmaxf(fmaf(p0, wa0[i], fmaf(p1, wb0[i], bb0[i])), 0.0f);
        #pragma unroll
        for (int i = 0; i < 4; ++i)
            r[4 + i] = fmaxf(fmaf(p0, wa1[i], fmaf(p1, wb1[i], bb1[i])), 0.0f);
        int i0 = __builtin_amdgcn_cvt_pk_fp8_f32(r[0], r[1], 0, false);
        i0     = __builtin_amdgcn_cvt_pk_fp8_f32(r[2], r[3], i0, true);
        int i1 = __builtin_amdgcn_cvt_pk_fp8_f32(r[4], r[5], 0, false);
        i1     = __builtin_amdgcn_cvt_pk_fp8_f32(r[6], r[7], i1, true);
        const int t = m >> 4, c = n0 >> 5, kk = n0 & 31;
        *(i32x2*)(H + (t * 2 + c) * 512 + ((kk >> 3) * 16 + (m & 15)) * 8) = (i32x2){i0, i1};
    }
    __syncthreads();

    // L2: 64 -> 256 (fp8)
    layer<true,  64, 2, 4, 1, 8,  2,  8, true,  0>(H, H + 4096, ws + F2_OFF, b2, 0, wave, lane);
    __syncthreads();
    // L3: 256 -> 512 (fp8), two od-halves, full h3 -> G (no split-K L4 needed)
    layer<true, 256, 4, 2, 2, 4,  8, 16, true,  0>(H + 4096, G, ws + F3_OFF,         b3,  0, wave, lane);
    layer<true, 256, 4, 2, 2, 4,  8, 16, true,  0>(H + 4096, G, ws + F3_OFF + 65536, b3, 16, wave, lane);
    __syncthreads();
    // L4: 512 -> 256 (fp8), full K in one pass
    layer<true, 512, 4, 2, 2, 4, 16,  8, true,  0>(G, H, ws + F4_OFF, b4, 0, wave, lane);
    __syncthreads();
    // L5: 256 -> 64 (fp8 in, bf16-FP out)
    layer<true, 256, 1, 2, 2, 4,  8,  2, true,  1>(H, G, ws + F5_OFF, b5, 0, wave, lane);
    __syncthreads();
    // L6: 64 -> 80 logits (bf16 in, f32 plain out @ G+8192)
    layer<false, 64, 1, 4, 1, 5,  2,  0, false, 2>(G, G + 8192, ws + F6_OFF,
                                                   (const float*)(ws + B6_OFF), 0, wave, lane);
    __syncthreads();

    // ---- epilogue: softmax(75) + 5x5x3 gather + sigmoid, 8 lanes per point ----
    const float* logitsS = (const float*)(G + 8192);
    const int p = tid >> 3;              // point within tile
    const int s = tid & 7;               // sub-lane
    const float p0 = posS[p * 2 + 0], p1 = posS[p * 2 + 1];
    const int tx0 = (int)(p0 / PI_F * 1023.0f);                 // == int(gx), ix = tx0 + dy
    const int ty0 = (int)((p1 + PI_F) / TWO_PI_F * 2047.0f);    // == int(gy), iy = ty0 + dx

    const float* lrow = logitsS + p * 80;
    float lv[10];
    float mx = -1e30f;
    #pragma unroll
    for (int i = 0; i < 10; ++i) {
        int f = s + i * 8;
        float v = (f < 75) ? lrow[f] : -1e30f;
        lv[i] = v;
        mx = fmaxf(mx, v);
    }
    mx = fmaxf(mx, __shfl_xor(mx, 1, 8));
    mx = fmaxf(mx, __shfl_xor(mx, 2, 8));
    mx = fmaxf(mx, __shfl_xor(mx, 4, 8));

    float den = 0.0f, x0 = 0.0f, x1 = 0.0f, x2 = 0.0f;
    #pragma unroll
    for (int i = 0; i < 10; ++i) {
        int f = s + i * 8;
        if (f < 75) {
            float e = __expf(lv[i] - mx);
            den += e;
            int c = f / 25, rr = f % 25, dy = rr / 5, dx = rr % 5;
            float g = grid_pos[((tx0 + dy) * 2052 + (ty0 + dx)) * 3 + c];
            if      (c == 0) x0 += e * g;
            else if (c == 1) x1 += e * g;
            else             x2 += e * g;
        }
    }
    #pragma unroll
    for (int mask = 1; mask < 8; mask <<= 1) {
        den += __shfl_xor(den, mask, 8);
        x0  += __shfl_xor(x0,  mask, 8);
        x1  += __shfl_xor(x1,  mask, 8);
        x2  += __shfl_xor(x2,  mask, 8);
    }
    if (s < 3) {
        float xv = (s == 0) ? x0 : (s == 1 ? x1 : x2);
        xv /= den;
        float sig = 1.0f / (1.0f + __expf(-xv));
        out[(m0 + p) * 3 + s] = (sig > 0.1f) ? sig * 255.0f : 0.0f;
    }
}

extern "C" void kernel_launch(void* const* d_in, const int* in_sizes, int n_in,
                              void* d_out, int out_size, void* d_ws, size_t ws_size,
                              hipStream_t stream) {
    const float* pos      = (const float*)d_in[0];
    const float* grid_pos = (const float*)d_in[1];
    const float* w1 = (const float*)d_in[2];
    const float* b1 = (const float*)d_in[3];
    const float* w2 = (const float*)d_in[4];
    const float* b2 = (const float*)d_in[5];
    const float* w3 = (const float*)d_in[6];
    const float* b3 = (const float*)d_in[7];
    const float* w4 = (const float*)d_in[8];
    const float* b4 = (const float*)d_in[9];
    const float* w5 = (const float*)d_in[10];
    const float* b5 = (const float*)d_in[11];
    const float* w6 = (const float*)d_in[12];
    const float* b6 = (const float*)d_in[13];
    char* ws = (char*)d_ws;
    float* out = (float*)d_out;

    prep_weights<<<(PREP_TOTAL + 255) / 256, 256, 0, stream>>>(w2, w3, w4, w5, w6, b6, ws);
    gridnet_fused<<<262144 / 64, 512, 0, stream>>>(pos, grid_pos, w1, b1, b2, b3, b4, b5, ws, out);
}

// Round 9
// 269.518 us; speedup vs baseline: 1.7825x; 1.0375x over previous
//
#include <hip/hip_runtime.h>

// ---------------------------------------------------------------------------
// GridNet fused forward: MLP (fp8/bf16 MFMA) + softmax + 5x5 gather + sigmoid
// B=262144, GS=(1024,2048), NS=5, layers 2-64-256-512-256-64-75
// R9: full A-tile register preload. R8 stalled on the weight stream: 1-deep
//     prefetch vs ~200cyc L2 latency, 39cyc MFMA per k-step -> SIMD idle.
//     Now all KT A-frags are issued before the k-loop (one latency hit per
//     layer). Tiles MT=2/NT=4/PTG=1 (OG=8): A-array <=16 frags = 32 VGPRs,
//     L4 split into two K=256 halves w/ carried acc. PTG=1 also removes
//     A-duplication (weight L2 traffic 570->300 KB/block).
//     R8: 213us, MfmaUtil 31%, no spill, 2 blk/CU.
// ---------------------------------------------------------------------------

#define PI_F     3.14159265358979323846f
#define TWO_PI_F 6.28318530717958647692f

typedef __attribute__((ext_vector_type(8))) short bf16x8;   // 8 bf16 = 4 VGPRs
typedef __attribute__((ext_vector_type(4))) short bf16x4;   // 8 B packed
typedef __attribute__((ext_vector_type(4))) float f32x4;    // MFMA C/D frag
typedef __attribute__((ext_vector_type(2))) int   i32x2;

__device__ __forceinline__ short f2bf(float f) {
    unsigned u = __builtin_bit_cast(unsigned, f);
    u += 0x7fffu + ((u >> 16) & 1u);            // round-nearest-even
    return (short)(u >> 16);
}

template<bool B, class T1, class T2> struct Cond { using T = T1; };
template<class T1, class T2> struct Cond<false, T1, T2> { using T = T2; };

__device__ __forceinline__ f32x4 mf(long a, long b, f32x4 c) {
    return __builtin_amdgcn_mfma_f32_16x16x32_fp8_fp8(a, b, c, 0, 0, 0);
}
__device__ __forceinline__ f32x4 mf(bf16x8 a, bf16x8 b, f32x4 c) {
    return __builtin_amdgcn_mfma_f32_16x16x32_bf16(a, b, c, 0, 0, 0);
}

// ws layout (BYTES). fp8 weights fragment-packed for MFMA A-operand:
//   frag f = ot*KTS + kt, 512 B; byte lane*8+e <-> W[k=kt*32+(lane>>4)*8+e][n=ot*16+(lane&15)]
#define F2_OFF 0
#define F3_OFF 16384
#define F4_OFF 147456
#define F5_OFF 278528
#define F6_OFF 294912
#define B6_OFF 305152
#define PREP_TOTAL 300112   // 294912 fp8 bytes + 5120 bf16 shorts + 80 f32

__global__ void prep_weights(const float* __restrict__ w2, const float* __restrict__ w3,
                             const float* __restrict__ w4, const float* __restrict__ w5,
                             const float* __restrict__ w6, const float* __restrict__ b6,
                             char* __restrict__ ws) {
    int idx = blockIdx.x * blockDim.x + threadIdx.x;
    if (idx >= PREP_TOTAL) return;
    if (idx < F6_OFF) {                          // fp8 sections, one byte each
        int lane = (idx >> 3) & 63, e = idx & 7;
        int f, kt, ot, n, k; float v;
        if (idx < F3_OFF) {
            f = idx >> 9; kt = f & 1; ot = f >> 1;
            n = ot * 16 + (lane & 15); k = kt * 32 + (lane >> 4) * 8 + e;
            v = w2[k * 256 + n];
        } else if (idx < F4_OFF) {
            int rel = idx - F3_OFF; int half = rel >> 16; int r2 = rel & 65535;
            f = r2 >> 9; kt = f & 7; ot = f >> 3;
            n = half * 256 + ot * 16 + (lane & 15); k = kt * 32 + (lane >> 4) * 8 + e;
            v = w3[k * 512 + n];
        } else if (idx < F5_OFF) {
            int rel = idx - F4_OFF; f = rel >> 9; kt = f & 15; ot = f >> 4;
            n = ot * 16 + (lane & 15); k = kt * 32 + (lane >> 4) * 8 + e;
            v = w4[k * 256 + n];
        } else {
            int rel = idx - F5_OFF; f = rel >> 9; kt = f & 7; ot = f >> 3;
            n = ot * 16 + (lane & 15); k = kt * 32 + (lane >> 4) * 8 + e;
            v = w5[k * 64 + n];
        }
        ws[idx] = (char)(__builtin_amdgcn_cvt_pk_fp8_f32(v, v, 0, false) & 0xff);
    } else if (idx < F6_OFF + 5120) {            // w6 bf16 frags (shorts)
        int s = idx - F6_OFF;
        int f = s >> 9, r = s & 511, lane = r >> 3, e = r & 7;
        int kt = f & 1, ot = f >> 1;
        int n = ot * 16 + (lane & 15), k = kt * 32 + (lane >> 4) * 8 + e;
        float v = (n < 75) ? w6[k * 75 + n] : 0.0f;
        ((short*)(ws + F6_OFF))[s] = f2bf(v);
    } else {                                     // padded bias6
        int n = idx - (F6_OFF + 5120);
        ((float*)(ws + B6_OFF))[n] = (n < 75) ? b6[n] : 0.0f;
    }
}

// Role-swapped layer: D[od][pt] = sum_k W^T[od][k] * act[k][pt] (+bias[od])
// Fragment-packed A (global/L2) and B (LDS), frag = 512 B (fp8) / 1024 B (bf16).
// ALL A-frags for the pass preloaded into registers before the k-loop (one
// L2-latency hit per layer). B read per-kt with 1-deep prefetch (LDS ~120cyc).
// 8 waves = OG od-groups x PTG pt-groups. KT = k-tiles this pass, KT0 = start
// k-tile, KTS = A-layout k-tiles/ot, KI = input-layout k-tiles/pt-tile.
// OM: 0=fp8-FP out, 1=bf16-FP out, 2=f32 plain (stride 80).
template<bool FP8, int KT, int MT, int NT, int PTG, int OG, int KTS, int KT0,
         int KI, int OUTKI, bool RELU, int OM, bool INIT, bool STORE>
__device__ __forceinline__ void layer(f32x4 (&acc)[MT][NT],
                                      const char* __restrict__ act, char* __restrict__ outP,
                                      const char* __restrict__ pack,
                                      const float* __restrict__ bias,
                                      const int otb0, const int wave, const int lane) {
    constexpr int FB = FP8 ? 512 : 1024;     // frag bytes
    constexpr int LB = FB / 64;              // bytes per lane per frag
    using frag_t = typename Cond<FP8, long, bf16x8>::T;
    const int og = wave / PTG;
    if (og >= OG) return;
    const int ptb = (wave % PTG) * (NT * 16);
    const int tj0 = ptb >> 4;
    const int otb = og * MT;
    const int lr = lane & 15, lq = lane >> 4;

    if (INIT) {
        #pragma unroll
        for (int i = 0; i < MT; ++i) {
            f32x4 bv = *(const f32x4*)(bias + (otb0 + otb + i) * 16 + lq * 4);
            #pragma unroll
            for (int j = 0; j < NT; ++j) acc[i][j] = bv;
        }
    }

    const char* ap = pack + (otb * KTS + KT0) * FB + lane * LB;
    const char* bp = act + (tj0 * KI + KT0) * FB + lane * LB;

    // ---- full A preload: MT*KT frags, all loads in flight at once ----
    frag_t a[MT][KT];
    #pragma unroll
    for (int i = 0; i < MT; ++i) {
        #pragma unroll
        for (int kt = 0; kt < KT; ++kt)
            a[i][kt] = *(const frag_t*)(ap + (i * KTS + kt) * FB);
    }

    frag_t b[NT];
    #pragma unroll
    for (int j = 0; j < NT; ++j) b[j] = *(const frag_t*)(bp + (j * KI) * FB);

    #pragma unroll
    for (int kt = 0; kt < KT; ++kt) {
        frag_t b2[NT];
        if (kt < KT - 1) {
            #pragma unroll
            for (int j = 0; j < NT; ++j)
                b2[j] = *(const frag_t*)(bp + (j * KI + kt + 1) * FB);
        }
        #pragma unroll
        for (int i = 0; i < MT; ++i) {
            #pragma unroll
            for (int j = 0; j < NT; ++j)
                acc[i][j] = mf(a[i][kt], b[j], acc[i][j]);
        }
        if (kt < KT - 1) {
            #pragma unroll
            for (int j = 0; j < NT; ++j) b[j] = b2[j];
        }
    }

    if (STORE) {
        #pragma unroll
        for (int i = 0; i < MT; ++i) {
            const int o0  = (otb0 + otb + i) * 16 + lq * 4;   // global out dim (4 consec)
            const int c   = o0 >> 5;                          // out k-tile
            const int kk3 = (o0 >> 3) & 3;
            const int e0  = o0 & 7;                           // 0 or 4
            #pragma unroll
            for (int j = 0; j < NT; ++j) {
                f32x4 v = acc[i][j];
                if (RELU) {
                    v[0] = fmaxf(v[0], 0.0f); v[1] = fmaxf(v[1], 0.0f);
                    v[2] = fmaxf(v[2], 0.0f); v[3] = fmaxf(v[3], 0.0f);
                }
                if (OM == 2) {
                    const int row = ptb + j * 16 + lr;
                    *(f32x4*)((float*)outP + row * 80 + o0) = v;
                } else if (OM == 0) {
                    int pk = __builtin_amdgcn_cvt_pk_fp8_f32(v[0], v[1], 0, false);
                    pk = __builtin_amdgcn_cvt_pk_fp8_f32(v[2], v[3], pk, true);
                    *(int*)(outP + ((tj0 + j) * OUTKI + c) * 512 + (kk3 * 16 + lr) * 8 + e0) = pk;
                } else {
                    bf16x4 pk = (bf16x4){ f2bf(v[0]), f2bf(v[1]), f2bf(v[2]), f2bf(v[3]) };
                    *(bf16x4*)((short*)outP + ((tj0 + j) * OUTKI + c) * 512 + (kk3 * 16 + lr) * 8 + e0) = pk;
                }
            }
        }
    }
}

__global__ __launch_bounds__(512, 4) void gridnet_fused(
    const float* __restrict__ pos, const float* __restrict__ grid_pos,
    const float* __restrict__ w1, const float* __restrict__ b1,
    const float* __restrict__ b2, const float* __restrict__ b3,
    const float* __restrict__ b4, const float* __restrict__ b5,
    const char* __restrict__ ws, float* __restrict__ out) {

    // H: h1 fp8 @0 (4KB), h2 fp8 @4096 (16KB); h4 fp8 reuses @0 (16KB).
    // G: h3 fp8 (32KB); then h5 bf16 @0 (8KB) and logits f32 @8192 (20KB).
    __shared__ __align__(16) char H[20480];
    __shared__ __align__(16) char G[32768];
    __shared__ float posS[128];

    const int tid  = threadIdx.x;
    const int wave = tid >> 6;
    const int lane = tid & 63;
    const int m0   = blockIdx.x * 64;

    if (tid < 128) posS[tid] = pos[m0 * 2 + tid];
    __syncthreads();

    // ---- layer 1 (2 -> 64) f32 VALU -> h1 fp8, fragment-packed (KI=2) ----
    {
        const int m = tid >> 3, g = tid & 7, n0 = g * 8;
        f32x4 wa0 = *(const f32x4*)(w1 + n0);
        f32x4 wa1 = *(const f32x4*)(w1 + n0 + 4);
        f32x4 wb0 = *(const f32x4*)(w1 + 64 + n0);
        f32x4 wb1 = *(const f32x4*)(w1 + 64 + n0 + 4);
        f32x4 bb0 = *(const f32x4*)(b1 + n0);
        f32x4 bb1 = *(const f32x4*)(b1 + n0 + 4);
        const float p0 = posS[m * 2 + 0], p1 = posS[m * 2 + 1];
        float r[8];
        #pragma unroll
        for (int i = 0; i < 4; ++i)
            r[i]     = fmaxf(fmaf(p0, wa0[i], fmaf(p1, wb0[i], bb0[i])), 0.0f);
        #pragma unroll
        for (int i = 0; i < 4; ++i)
            r[4 + i] = fmaxf(fmaf(p0, wa1[i], fmaf(p1, wb1[i], bb1[i])), 0.0f);
        int i0 = __builtin_amdgcn_cvt_pk_fp8_f32(r[0], r[1], 0, false);
        i0     = __builtin_amdgcn_cvt_pk_fp8_f32(r[2], r[3], i0, true);
        int i1 = __builtin_amdgcn_cvt_pk_fp8_f32(r[4], r[5], 0, false);
        i1     = __builtin_amdgcn_cvt_pk_fp8_f32(r[6], r[7], i1, true);
        const int t = m >> 4, c = n0 >> 5, kk = n0 & 31;
        *(i32x2*)(H + (t * 2 + c) * 512 + ((kk >> 3) * 16 + (m & 15)) * 8) = (i32x2){i0, i1};
    }
    __syncthreads();

    // L2: 64 -> 256 (fp8); OG=8 x MT=2 = 16 ot, PTG=1/NT=4
    {
        f32x4 acc[2][4];
        layer<true, 2, 2, 4, 1, 8,  2, 0,  2,  8, true, 0, true, true>(
            acc, H, H + 4096, ws + F2_OFF, b2, 0, wave, lane);
    }
    __syncthreads();

    // L3: 256 -> 512 (fp8), two od-halves (16 ot each), full h3 -> G
    {
        f32x4 acc[2][4];
        layer<true, 8, 2, 4, 1, 8,  8, 0,  8, 16, true, 0, true, true>(
            acc, H + 4096, G, ws + F3_OFF, b3, 0, wave, lane);
    }
    {
        f32x4 acc[2][4];
        layer<true, 8, 2, 4, 1, 8,  8, 0,  8, 16, true, 0, true, true>(
            acc, H + 4096, G, ws + F3_OFF + 65536, b3, 16, wave, lane);
    }
    __syncthreads();

    // L4: 512 -> 256 (fp8), two K=256 halves, acc carried (A-array stays <=16 frags)
    {
        f32x4 acc[2][4];
        layer<true, 8, 2, 4, 1, 8, 16, 0, 16,  8, true, 0, true, false>(
            acc, G, H, ws + F4_OFF, b4, 0, wave, lane);
        layer<true, 8, 2, 4, 1, 8, 16, 8, 16,  8, true, 0, false, true>(
            acc, G, H, ws + F4_OFF, b4, 0, wave, lane);
    }
    __syncthreads();

    // L5: 256 -> 64 (fp8 in, bf16-FP out to G)
    {
        f32x4 acc[1][2];
        layer<true, 8, 1, 2, 2, 4,  8, 0,  8,  2, true, 1, true, true>(
            acc, H, G, ws + F5_OFF, b5, 0, wave, lane);
    }
    __syncthreads();

    // L6: 64 -> 80 logits (bf16 in, f32 plain out @ G+8192)
    {
        f32x4 acc[1][4];
        layer<false, 2, 1, 4, 1, 5,  2, 0,  2,  0, false, 2, true, true>(
            acc, G, G + 8192, ws + F6_OFF, (const float*)(ws + B6_OFF), 0, wave, lane);
    }
    __syncthreads();

    // ---- epilogue: softmax(75) + 5x5x3 gather + sigmoid, 8 lanes per point ----
    const float* logitsS = (const float*)(G + 8192);
    const int p = tid >> 3;              // point within tile
    const int s = tid & 7;               // sub-lane
    const float p0 = posS[p * 2 + 0], p1 = posS[p * 2 + 1];
    const int tx0 = (int)(p0 / PI_F * 1023.0f);                 // == int(gx), ix = tx0 + dy
    const int ty0 = (int)((p1 + PI_F) / TWO_PI_F * 2047.0f);    // == int(gy), iy = ty0 + dx

    const float* lrow = logitsS + p * 80;
    float lv[10];
    float mx = -1e30f;
    #pragma unroll
    for (int i = 0; i < 10; ++i) {
        int f = s + i * 8;
        float v = (f < 75) ? lrow[f] : -1e30f;
        lv[i] = v;
        mx = fmaxf(mx, v);
    }
    mx = fmaxf(mx, __shfl_xor(mx, 1, 8));
    mx = fmaxf(mx, __shfl_xor(mx, 2, 8));
    mx = fmaxf(mx, __shfl_xor(mx, 4, 8));

    float den = 0.0f, x0 = 0.0f, x1 = 0.0f, x2 = 0.0f;
    #pragma unroll
    for (int i = 0; i < 10; ++i) {
        int f = s + i * 8;
        if (f < 75) {
            float e = __expf(lv[i] - mx);
            den += e;
            int c = f / 25, rr = f % 25, dy = rr / 5, dx = rr % 5;
            float g = grid_pos[((tx0 + dy) * 2052 + (ty0 + dx)) * 3 + c];
            if      (c == 0) x0 += e * g;
            else if (c == 1) x1 += e * g;
            else             x2 += e * g;
        }
    }
    #pragma unroll
    for (int mask = 1; mask < 8; mask <<= 1) {
        den += __shfl_xor(den, mask, 8);
        x0  += __shfl_xor(x0,  mask, 8);
        x1  += __shfl_xor(x1,  mask, 8);
        x2  += __shfl_xor(x2,  mask, 8);
    }
    if (s < 3) {
        float xv = (s == 0) ? x0 : (s == 1 ? x1 : x2);
        xv /= den;
        float sig = 1.0f / (1.0f + __expf(-xv));
        out[(m0 + p) * 3 + s] = (sig > 0.1f) ? sig * 255.0f : 0.0f;
    }
}

extern "C" void kernel_launch(void* const* d_in, const int* in_sizes, int n_in,
                              void* d_out, int out_size, void* d_ws, size_t ws_size,
                              hipStream_t stream) {
    const float* pos      = (const float*)d_in[0];
    const float* grid_pos = (const float*)d_in[1];
    const float* w1 = (const float*)d_in[2];
    const float* b1 = (const float*)d_in[3];
    const float* w2 = (const float*)d_in[4];
    const float* b2 = (const float*)d_in[5];
    const float* w3 = (const float*)d_in[6];
    const float* b3 = (const float*)d_in[7];
    const float* w4 = (const float*)d_in[8];
    const float* b4 = (const float*)d_in[9];
    const float* w5 = (const float*)d_in[10];
    const float* b5 = (const float*)d_in[11];
    const float* w6 = (const float*)d_in[12];
    const float* b6 = (const float*)d_in[13];
    char* ws = (char*)d_ws;
    float* out = (float*)d_out;

    prep_weights<<<(PREP_TOTAL + 255) / 256, 256, 0, stream>>>(w2, w3, w4, w5, w6, b6, ws);
    gridnet_fused<<<262144 / 64, 512, 0, stream>>>(pos, grid_pos, w1, b1, b2, b3, b4, b5, ws, out);
}